// Round 10
// baseline (381.546 us; speedup 1.0000x reference)
//
#include <hip/hip_runtime.h>
#include <math.h>

// LSTMClassifier fused kernel for MI355X (gfx950) — round 9
// fp16 2-term MFMA: A-side (x, h) staged as SINGLE fp16 plane (state
// perturbation 2^-11, damped by forget gate); B-side (weights) as fp16
// hi + lo*2^11 (lo pre-scaled out of the fp16 subnormal range), lo-terms
// accumulated separately and combined as g = accH + accL/2048.
// 16 MFMA/wave/step (was 24), 4 LDS b128 reads/wave/step (was 8).
// Structure from round 8 (passed, 9.8e-4): gate-permuted N layout (wave w
// owns all 4 gates of units 8w..8w+7), ONE barrier/step, cross-step x
// pipeline, 512 threads, grid=256, 4 batch/block (A-rows 0,4,8,12).

#define S_LEN  512
#define I_DIM  50
#define H_DIM  64
#define BB     4
#define KROW   40          // A-row stride in fp16 elems (80B)
#define F1_DIM 32
#define C_DIM  2

typedef __attribute__((ext_vector_type(8))) _Float16 f16x8;
typedef __attribute__((ext_vector_type(4))) float    f32x4;

#define ILO (1.0f / 2048.0f)

__device__ __forceinline__ float fast_rcp(float x) { return __builtin_amdgcn_rcpf(x); }
__device__ __forceinline__ float sigm(float v) { return fast_rcp(1.0f + __expf(-v)); }
__device__ __forceinline__ float tanh_fast(float v) {
    return 1.0f - 2.0f * fast_rcp(__expf(2.0f * v) + 1.0f);
}

// Weight fragment pair: hi = fp16(w), lo = fp16((w - hi) * 2048).
// B[k][n] = W[row][k]; lane holds k = ktg*32 + hk*8 + j.
// ktg 0,1 -> W_ih (k<50, else 0); ktg 2,3 -> W_hh (k-64).
__device__ __forceinline__ void load_wfrag(const float* __restrict__ Wih,
                                           const float* __restrict__ Whh,
                                           int ktg, int row, int hk,
                                           f16x8& bh, f16x8& bl) {
    #pragma unroll
    for (int j = 0; j < 8; ++j) {
        const int kk = ktg * 32 + hk * 8 + j;
        float wv;
        if (ktg < 2) wv = (kk < I_DIM) ? Wih[row * I_DIM + kk] : 0.0f;
        else         wv = Whh[row * H_DIM + (kk - 64)];
        const _Float16 h = (_Float16)wv;
        bh[j] = h;
        bl[j] = (_Float16)((wv - (float)h) * 2048.0f);
    }
}

__global__ __launch_bounds__(512, 2)
void lstm_mfma(const float* __restrict__ x,
               const float* __restrict__ W_ih, const float* __restrict__ W_hh,
               const float* __restrict__ b_ih, const float* __restrict__ b_hh,
               const float* __restrict__ W1,  const float* __restrict__ b1,
               const float* __restrict__ W2,  const float* __restrict__ b2,
               float* __restrict__ out)
{
    // A-operand stages, double-buffered, SINGLE fp16 plane each.
    __shared__ __align__(16) _Float16 Hst[2][2][16][KROW];
    __shared__ __align__(16) _Float16 Xst[2][2][16][KROW];
    __shared__ float f1buf[BB][F1_DIM];

    const int u  = threadIdx.x;      // 0..511
    const int w  = u >> 6;           // wave 0..7
    const int l  = u & 63;
    const int c  = l & 15;           // n-col within tile / m-row for A-read
    const int hk = l >> 4;           // k-quarter; = batch in cell phase
    const int b0 = blockIdx.x * BB;

    // permuted N mapping: wave w tileA col c -> gate (c>>3),   unit 8w+(c&7)
    //                            tileB col c -> gate 2+(c>>3), unit 8w+(c&7)
    const int uu = 8 * w + (c & 7);
    const int r0 = ((c >> 3) + 0) * H_DIM + uu;   // global W row, tile A
    const int r1 = ((c >> 3) + 2) * H_DIM + uu;   // global W row, tile B

    // ---- weight fragments (resident): x-ktiles 0,1 / h-ktiles 2,3 ----
#define LW(nm, ktg, row) f16x8 nm##h, nm##l; \
    load_wfrag(W_ih, W_hh, ktg, row, hk, nm##h, nm##l);
    LW(wx0a, 0, r0) LW(wx1a, 1, r0) LW(wh0a, 2, r0) LW(wh1a, 3, r0)
    LW(wx0b, 0, r1) LW(wx1b, 1, r1) LW(wh0b, 2, r1) LW(wh1b, 3, r1)
#undef LW

    float bA = b_ih[r0] + b_hh[r0];
    float bB = b_ih[r1] + b_hh[r1];
    float cst = 0.0f;                // cell state: (batch hk, unit 8w+c), c<8

    // ---- x staging role: lanes c>=8, sv<200 -> (batch pb, input pi) ----
    const int  sv  = 32 * w + 8 * hk + (c & 7);
    const bool isp = (c >= 8) && (sv < 200);
    int pb = sv / I_DIM; if (pb > 3) pb = 3;
    const int pi  = sv - pb * I_DIM;
    const float* xp = x + ((size_t)(b0 + pb) * S_LEN) * I_DIM + pi;
    const int skt = pi >> 5, skc = pi & 31, srw = 4 * pb;

    // ---- zero staging (h0=0, pad cols, unused rows) ----
    for (int i = u; i < 1280; i += 512) {
        ((unsigned*)Hst)[i] = 0u; ((unsigned*)Xst)[i] = 0u;
    }
    __syncthreads();
    if (isp) {                       // stage x(0)->X[0], x(1)->X[1]
        Xst[0][skt][srw][skc] = (_Float16)xp[0];
        Xst[1][skt][srw][skc] = (_Float16)xp[I_DIM];
    }
    __syncthreads();

#define MM2(ACC, LACC, A, WN) \
    ACC  = __builtin_amdgcn_mfma_f32_16x16x32_f16(A, WN##h, ACC,  0, 0, 0); \
    LACC = __builtin_amdgcn_mfma_f32_16x16x32_f16(A, WN##l, LACC, 0, 0, 0);

    // ---- prologue: accA = bias + x(0)·W_ih from X[0] ----
    f32x4 aA0, aA1, lA0, lA1, aB0, aB1, lB0, lB1;
    aA0[0]=bA; aA0[1]=bA; aA0[2]=bA; aA0[3]=bA;
    aA1[0]=bB; aA1[1]=bB; aA1[2]=bB; aA1[3]=bB;
    lA0 = (f32x4){0.f,0.f,0.f,0.f}; lA1 = lA0;
    aB0 = aA0; aB1 = aA1; lB0 = lA0; lB1 = lA1;   // init (overwritten)
    {
        const f16x8 xf0 = *(const f16x8*)&Xst[0][0][c][hk * 8];
        const f16x8 xf1 = *(const f16x8*)&Xst[0][1][c][hk * 8];
        MM2(aA0, lA0, xf0, wx0a) MM2(aA0, lA0, xf1, wx1a)
        MM2(aA1, lA1, xf0, wx0b) MM2(aA1, lA1, xf1, wx1b)
    }
    __syncthreads();                 // X[0] reads done before step-0 staging

    // ---- scan; ONE barrier per step; unrolled x2 for acc handoff ----
#define STEP(T, AP0, AP1, LP0, LP1, AN0, AN1, LN0, LN1, CUR, NXT) { \
    float xnext = 0.0f; \
    const bool dox = isp && ((T) + 2 < S_LEN); \
    if (dox) xnext = xp[(size_t)((T) + 2) * I_DIM];      /* issue early */ \
    const f16x8 ah0 = *(const f16x8*)&Hst[CUR][0][c][hk * 8]; \
    const f16x8 ah1 = *(const f16x8*)&Hst[CUR][1][c][hk * 8]; \
    const f16x8 xh0 = *(const f16x8*)&Xst[NXT][0][c][hk * 8]; \
    const f16x8 xh1 = *(const f16x8*)&Xst[NXT][1][c][hk * 8]; \
    MM2(AP0, LP0, ah0, wh0a) MM2(AP0, LP0, ah1, wh1a)    /* h-part */ \
    MM2(AP1, LP1, ah0, wh0b) MM2(AP1, LP1, ah1, wh1b) \
    const float v0 = AP0[0] + ILO * LP0[0]; \
    const float v1 = AP1[0] + ILO * LP1[0]; \
    const float y0 = __shfl_xor(v0, 8); \
    const float y1 = __shfl_xor(v1, 8); \
    AN0[0]=bA; AN0[1]=bA; AN0[2]=bA; AN0[3]=bA; \
    AN1[0]=bB; AN1[1]=bB; AN1[2]=bB; AN1[3]=bB; \
    LN0 = (f32x4){0.f,0.f,0.f,0.f}; LN1 = LN0; \
    MM2(AN0, LN0, xh0, wx0a) MM2(AN0, LN0, xh1, wx1a)    /* x-part t+1 */ \
    MM2(AN1, LN1, xh0, wx0b) MM2(AN1, LN1, xh1, wx1b) \
    const float gi = sigm(v0), gf = sigm(y0);            /* i,f  (c<8) */ \
    const float gg = tanh_fast(v1), go = sigm(y1);       /* g~,o (c<8) */ \
    if (c < 8) { \
        cst = fmaf(gf, cst, gi * gg); \
        const float hv = go * tanh_fast(cst); \
        Hst[NXT][w >> 2][4 * hk][8 * (w & 3) + c] = (_Float16)hv; \
    } else if (dox) { \
        Xst[CUR][skt][srw][skc] = (_Float16)xnext; \
    } \
    __syncthreads(); \
}

    for (int t = 0; t < S_LEN; t += 2) {
        asm volatile("" : "+v"(wx0ah), "+v"(wx0al), "+v"(wx1ah), "+v"(wx1al),
                          "+v"(wh0ah), "+v"(wh0al), "+v"(wh1ah), "+v"(wh1al));
        asm volatile("" : "+v"(wx0bh), "+v"(wx0bl), "+v"(wx1bh), "+v"(wx1bl),
                          "+v"(wh0bh), "+v"(wh0bl), "+v"(wh1bh), "+v"(wh1bl));
        asm volatile("" : "+v"(bA), "+v"(bB));
        STEP(t,     aA0, aA1, lA0, lA1, aB0, aB1, lB0, lB1, 0, 1)
        STEP(t + 1, aB0, aB1, lB0, lB1, aA0, aA1, lA0, lA1, 1, 0)
    }
#undef STEP
#undef MM2

    // ---- classifier head; h_last (fp16) in H[0], rows 4b ----
    if (u < BB * F1_DIM) {           // 128 threads
        const int b = u >> 5, f = u & 31;
        float acc = b1[f];
        #pragma unroll
        for (int j = 0; j < H_DIM; ++j) {
            const float hj = (float)Hst[0][j >> 5][4 * b][j & 31];
            acc = fmaf(hj, W1[f * H_DIM + j], acc);
        }
        f1buf[b][f] = fmaxf(acc, 0.0f);
    }
    __syncthreads();
    if (u < BB * C_DIM) {            // 8 threads
        const int b = u >> 1, cl = u & 1;
        float acc = b2[cl];
        #pragma unroll
        for (int f = 0; f < F1_DIM; ++f)
            acc = fmaf(f1buf[b][f], W2[cl * F1_DIM + f], acc);
        out[(size_t)(b0 + b) * C_DIM + cl] = acc;
    }
}

extern "C" void kernel_launch(void* const* d_in, const int* in_sizes, int n_in,
                              void* d_out, int out_size, void* d_ws, size_t ws_size,
                              hipStream_t stream) {
    const float* x   = (const float*)d_in[0];
    const float* Wih = (const float*)d_in[1];
    const float* Whh = (const float*)d_in[2];
    const float* bih = (const float*)d_in[3];
    const float* bhh = (const float*)d_in[4];
    const float* W1  = (const float*)d_in[5];
    const float* b1  = (const float*)d_in[6];
    const float* W2  = (const float*)d_in[7];
    const float* b2  = (const float*)d_in[8];
    float* out = (float*)d_out;

    hipLaunchKernelGGL(lstm_mfma, dim3(256), dim3(512), 0, stream,
                       x, Wih, Whh, bih, bhh, W1, b1, W2, b2, out);
}

// Round 11
// 372.527 us; speedup vs baseline: 1.0242x; 1.0242x over previous
//
#include <hip/hip_runtime.h>
#include <math.h>

// LSTMClassifier fused kernel for MI355X (gfx950) — round 10
// = round 9 (fp16 2-term MFMA) MINUS all per-iteration asm register pins
// (they forced AGPR->VGPR copy storms, ~128 extra VALU ops/step), and bias
// folded at gate-combine time (accumulators init to 0, stay in AGPRs).
// A-side (x, h) staged as single fp16 plane; weights as fp16 hi + lo*2^11;
// g = accH + accL/2048 + bias. 16 MFMA + 4 ds_read_b128 /wave/step.
// Gate-permuted N layout (wave w owns all 4 gates of units 8w..8w+7),
// ONE barrier/step, cross-step x pipeline, 512 thr, grid=256, 4 batch/block.

#define S_LEN  512
#define I_DIM  50
#define H_DIM  64
#define BB     4
#define KROW   40          // A-row stride in fp16 elems (80B)
#define F1_DIM 32
#define C_DIM  2

typedef __attribute__((ext_vector_type(8))) _Float16 f16x8;
typedef __attribute__((ext_vector_type(4))) float    f32x4;

#define ILO (1.0f / 2048.0f)

__device__ __forceinline__ float fast_rcp(float x) { return __builtin_amdgcn_rcpf(x); }
__device__ __forceinline__ float sigm(float v) { return fast_rcp(1.0f + __expf(-v)); }
__device__ __forceinline__ float tanh_fast(float v) {
    return 1.0f - 2.0f * fast_rcp(__expf(2.0f * v) + 1.0f);
}

// Weight fragment pair: hi = fp16(w), lo = fp16((w - hi) * 2048).
// B[k][n] = W[row][k]; lane holds k = ktg*32 + hk*8 + j.
// ktg 0,1 -> W_ih (k<50, else 0); ktg 2,3 -> W_hh (k-64).
__device__ __forceinline__ void load_wfrag(const float* __restrict__ Wih,
                                           const float* __restrict__ Whh,
                                           int ktg, int row, int hk,
                                           f16x8& bh, f16x8& bl) {
    #pragma unroll
    for (int j = 0; j < 8; ++j) {
        const int kk = ktg * 32 + hk * 8 + j;
        float wv;
        if (ktg < 2) wv = (kk < I_DIM) ? Wih[row * I_DIM + kk] : 0.0f;
        else         wv = Whh[row * H_DIM + (kk - 64)];
        const _Float16 h = (_Float16)wv;
        bh[j] = h;
        bl[j] = (_Float16)((wv - (float)h) * 2048.0f);
    }
}

__global__ __launch_bounds__(512, 2)
void lstm_mfma(const float* __restrict__ x,
               const float* __restrict__ W_ih, const float* __restrict__ W_hh,
               const float* __restrict__ b_ih, const float* __restrict__ b_hh,
               const float* __restrict__ W1,  const float* __restrict__ b1,
               const float* __restrict__ W2,  const float* __restrict__ b2,
               float* __restrict__ out)
{
    // A-operand stages, double-buffered, single fp16 plane each.
    __shared__ __align__(16) _Float16 Hst[2][2][16][KROW];
    __shared__ __align__(16) _Float16 Xst[2][2][16][KROW];
    __shared__ float f1buf[BB][F1_DIM];

    const int u  = threadIdx.x;      // 0..511
    const int w  = u >> 6;           // wave 0..7
    const int l  = u & 63;
    const int c  = l & 15;           // n-col within tile / m-row for A-read
    const int hk = l >> 4;           // k-quarter; = batch in cell phase
    const int b0 = blockIdx.x * BB;

    // permuted N mapping: wave w tileA col c -> gate (c>>3),   unit 8w+(c&7)
    //                            tileB col c -> gate 2+(c>>3), unit 8w+(c&7)
    const int uu = 8 * w + (c & 7);
    const int r0 = ((c >> 3) + 0) * H_DIM + uu;   // global W row, tile A
    const int r1 = ((c >> 3) + 2) * H_DIM + uu;   // global W row, tile B

    // ---- weight fragments (resident; no pins -> free to live in AGPRs) ----
#define LW(nm, ktg, row) f16x8 nm##h, nm##l; \
    load_wfrag(W_ih, W_hh, ktg, row, hk, nm##h, nm##l);
    LW(wx0a, 0, r0) LW(wx1a, 1, r0) LW(wh0a, 2, r0) LW(wh1a, 3, r0)
    LW(wx0b, 0, r1) LW(wx1b, 1, r1) LW(wh0b, 2, r1) LW(wh1b, 3, r1)
#undef LW

    const float bA = b_ih[r0] + b_hh[r0];
    const float bB = b_ih[r1] + b_hh[r1];
    float cst = 0.0f;                // cell state: (batch hk, unit 8w+c), c<8

    // ---- x staging role: lanes c>=8, sv<200 -> (batch pb, input pi) ----
    const int  sv  = 32 * w + 8 * hk + (c & 7);
    const bool isp = (c >= 8) && (sv < 200);
    int pb = sv / I_DIM; if (pb > 3) pb = 3;
    const int pi  = sv - pb * I_DIM;
    const float* xp = x + ((size_t)(b0 + pb) * S_LEN) * I_DIM + pi;
    const int skt = pi >> 5, skc = pi & 31, srw = 4 * pb;

    // ---- zero staging (h0=0, pad cols, unused rows) ----
    for (int i = u; i < 1280; i += 512) {
        ((unsigned*)Hst)[i] = 0u; ((unsigned*)Xst)[i] = 0u;
    }
    __syncthreads();
    if (isp) {                       // stage x(0)->X[0], x(1)->X[1]
        Xst[0][skt][srw][skc] = (_Float16)xp[0];
        Xst[1][skt][srw][skc] = (_Float16)xp[I_DIM];
    }
    __syncthreads();

#define MM2(ACC, LACC, A, WN) \
    ACC  = __builtin_amdgcn_mfma_f32_16x16x32_f16(A, WN##h, ACC,  0, 0, 0); \
    LACC = __builtin_amdgcn_mfma_f32_16x16x32_f16(A, WN##l, LACC, 0, 0, 0);

    // ---- prologue: accA = x(0)·W_ih from X[0] (bias added at combine) ----
    f32x4 aA0, aA1, lA0, lA1, aB0, aB1, lB0, lB1;
    aA0 = (f32x4){0.f,0.f,0.f,0.f}; aA1 = aA0; lA0 = aA0; lA1 = aA0;
    aB0 = aA0; aB1 = aA0; lB0 = aA0; lB1 = aA0;   // init (overwritten)
    {
        const f16x8 xf0 = *(const f16x8*)&Xst[0][0][c][hk * 8];
        const f16x8 xf1 = *(const f16x8*)&Xst[0][1][c][hk * 8];
        MM2(aA0, lA0, xf0, wx0a) MM2(aA0, lA0, xf1, wx1a)
        MM2(aA1, lA1, xf0, wx0b) MM2(aA1, lA1, xf1, wx1b)
    }
    __syncthreads();                 // X[0] reads done before step-0 staging

    // ---- scan; ONE barrier per step; unrolled x2 for acc handoff ----
#define STEP(T, AP0, AP1, LP0, LP1, AN0, AN1, LN0, LN1, CUR, NXT) { \
    float xnext = 0.0f; \
    const bool dox = isp && ((T) + 2 < S_LEN); \
    if (dox) xnext = xp[(size_t)((T) + 2) * I_DIM];      /* issue early */ \
    const f16x8 ah0 = *(const f16x8*)&Hst[CUR][0][c][hk * 8]; \
    const f16x8 ah1 = *(const f16x8*)&Hst[CUR][1][c][hk * 8]; \
    const f16x8 xh0 = *(const f16x8*)&Xst[NXT][0][c][hk * 8]; \
    const f16x8 xh1 = *(const f16x8*)&Xst[NXT][1][c][hk * 8]; \
    MM2(AP0, LP0, ah0, wh0a) MM2(AP0, LP0, ah1, wh1a)    /* h-part */ \
    MM2(AP1, LP1, ah0, wh0b) MM2(AP1, LP1, ah1, wh1b) \
    const float v0 = AP0[0] + fmaf(ILO, LP0[0], bA); \
    const float v1 = AP1[0] + fmaf(ILO, LP1[0], bB); \
    const float y0 = __shfl_xor(v0, 8); \
    const float y1 = __shfl_xor(v1, 8); \
    AN0 = (f32x4){0.f,0.f,0.f,0.f}; AN1 = AN0; \
    LN0 = AN0; LN1 = AN0; \
    MM2(AN0, LN0, xh0, wx0a) MM2(AN0, LN0, xh1, wx1a)    /* x-part t+1 */ \
    MM2(AN1, LN1, xh0, wx0b) MM2(AN1, LN1, xh1, wx1b) \
    const float gi = sigm(v0), gf = sigm(y0);            /* i,f  (c<8) */ \
    const float gg = tanh_fast(v1), go = sigm(y1);       /* g~,o (c<8) */ \
    if (c < 8) { \
        cst = fmaf(gf, cst, gi * gg); \
        const float hv = go * tanh_fast(cst); \
        Hst[NXT][w >> 2][4 * hk][8 * (w & 3) + c] = (_Float16)hv; \
    } else if (dox) { \
        Xst[CUR][skt][srw][skc] = (_Float16)xnext; \
    } \
    __syncthreads(); \
}

    for (int t = 0; t < S_LEN; t += 2) {
        STEP(t,     aA0, aA1, lA0, lA1, aB0, aB1, lB0, lB1, 0, 1)
        STEP(t + 1, aB0, aB1, lB0, lB1, aA0, aA1, lA0, lA1, 1, 0)
    }
#undef STEP
#undef MM2

    // ---- classifier head; h_last (fp16) in H[0], rows 4b ----
    if (u < BB * F1_DIM) {           // 128 threads
        const int b = u >> 5, f = u & 31;
        float acc = b1[f];
        #pragma unroll
        for (int j = 0; j < H_DIM; ++j) {
            const float hj = (float)Hst[0][j >> 5][4 * b][j & 31];
            acc = fmaf(hj, W1[f * H_DIM + j], acc);
        }
        f1buf[b][f] = fmaxf(acc, 0.0f);
    }
    __syncthreads();
    if (u < BB * C_DIM) {            // 8 threads
        const int b = u >> 1, cl = u & 1;
        float acc = b2[cl];
        #pragma unroll
        for (int f = 0; f < F1_DIM; ++f)
            acc = fmaf(f1buf[b][f], W2[cl * F1_DIM + f], acc);
        out[(size_t)(b0 + b) * C_DIM + cl] = acc;
    }
}

extern "C" void kernel_launch(void* const* d_in, const int* in_sizes, int n_in,
                              void* d_out, int out_size, void* d_ws, size_t ws_size,
                              hipStream_t stream) {
    const float* x   = (const float*)d_in[0];
    const float* Wih = (const float*)d_in[1];
    const float* Whh = (const float*)d_in[2];
    const float* bih = (const float*)d_in[3];
    const float* bhh = (const float*)d_in[4];
    const float* W1  = (const float*)d_in[5];
    const float* b1  = (const float*)d_in[6];
    const float* W2  = (const float*)d_in[7];
    const float* b2  = (const float*)d_in[8];
    float* out = (float*)d_out;

    hipLaunchKernelGGL(lstm_mfma, dim3(256), dim3(512), 0, stream,
                       x, Wih, Whh, bih, bhh, W1, b1, W2, b2, out);
}

// Round 12
// 332.680 us; speedup vs baseline: 1.1469x; 1.1198x over previous
//
#include <hip/hip_runtime.h>
#include <math.h>

// LSTMClassifier fused kernel for MI355X (gfx950) — round 11
// fp16 2-term MFMA (r10 math, proven absmax 9.77e-4) at 4 waves/SIMD:
// 1024 threads = 16 waves; wave w owns ONE N-tile = all 4 gates of units
// 4w..4w+3 (col = gate*4 + unit). 4 h-MFMA + 4 x-MFMA + 4 ds_read_b128 per
// wave per step; gates assembled in-wave via 3 shfl_xor; cell on lanes c<4.
// Latency-bound fix: TLP (4 waves/SIMD) hides ds/MFMA/transcendental latency
// that 2 waves/SIMD could not (r9/r10 regression).
// B=1024, S=512, I=50, H=64, F1=32, C=2; grid=256, 4 batch/block (rows 0,4,8,12).

#define S_LEN  512
#define I_DIM  50
#define H_DIM  64
#define BB     4
#define KROW   40          // A-row stride in fp16 elems (80B, 16B-aligned)
#define F1_DIM 32
#define C_DIM  2

typedef __attribute__((ext_vector_type(8))) _Float16 f16x8;
typedef __attribute__((ext_vector_type(4))) float    f32x4;

#define ILO (1.0f / 2048.0f)

__device__ __forceinline__ float fast_rcp(float x) { return __builtin_amdgcn_rcpf(x); }
__device__ __forceinline__ float sigm(float v) { return fast_rcp(1.0f + __expf(-v)); }
__device__ __forceinline__ float tanh_fast(float v) {
    return 1.0f - 2.0f * fast_rcp(__expf(2.0f * v) + 1.0f);
}

// Weight fragment pair: hi = fp16(w), lo = fp16((w - hi) * 2048).
// B[k][n] = W[row][k]; lane holds k = ktg*32 + hk*8 + j.
// ktg 0,1 -> W_ih (k<50, else 0); ktg 2,3 -> W_hh (k-64).
__device__ __forceinline__ void load_wfrag(const float* __restrict__ Wih,
                                           const float* __restrict__ Whh,
                                           int ktg, int row, int hk,
                                           f16x8& bh, f16x8& bl) {
    #pragma unroll
    for (int j = 0; j < 8; ++j) {
        const int kk = ktg * 32 + hk * 8 + j;
        float wv;
        if (ktg < 2) wv = (kk < I_DIM) ? Wih[row * I_DIM + kk] : 0.0f;
        else         wv = Whh[row * H_DIM + (kk - 64)];
        const _Float16 h = (_Float16)wv;
        bh[j] = h;
        bl[j] = (_Float16)((wv - (float)h) * 2048.0f);
    }
}

__global__ __launch_bounds__(1024, 4)
void lstm_mfma(const float* __restrict__ x,
               const float* __restrict__ W_ih, const float* __restrict__ W_hh,
               const float* __restrict__ b_ih, const float* __restrict__ b_hh,
               const float* __restrict__ W1,  const float* __restrict__ b1,
               const float* __restrict__ W2,  const float* __restrict__ b2,
               float* __restrict__ out)
{
    // A-operand stages, double-buffered, single fp16 plane each.
    __shared__ __align__(16) _Float16 Hst[2][2][16][KROW];
    __shared__ __align__(16) _Float16 Xst[2][2][16][KROW];
    __shared__ float f1buf[BB][F1_DIM];

    const int u  = threadIdx.x;      // 0..1023
    const int w  = u >> 6;           // wave 0..15
    const int l  = u & 63;
    const int c  = l & 15;           // n-col within tile / m-row for A-read
    const int hk = l >> 4;           // k-quarter; = batch in cell phase
    const int b0 = blockIdx.x * BB;

    // N mapping: wave w col c -> gate g = c>>2, unit = 4w + (c&3)
    const int g    = c >> 2;
    const int unit = 4 * w + (c & 3);
    const int r    = g * H_DIM + unit;      // global weight row

    // ---- weight fragments (resident): one tile, 4 ktiles, hi+lo ----
#define LW(nm, ktg) f16x8 nm##h, nm##l; \
    load_wfrag(W_ih, W_hh, ktg, r, hk, nm##h, nm##l);
    LW(wx0, 0) LW(wx1, 1) LW(wh0, 2) LW(wh1, 3)
#undef LW

    const float bias = b_ih[r] + b_hh[r];
    float cst = 0.0f;                // cell state: (batch hk, unit), lanes c<4

    // ---- x staging role: lanes c>=8 -> sid 0..511, active sid<200 ----
    const int  sid = 32 * w + 8 * hk + (c - 8);
    const bool isp = (c >= 8) && (sid < BB * I_DIM);
    int pb = isp ? (sid / I_DIM) : 0;
    const int pi  = isp ? (sid - pb * I_DIM) : 0;
    const float* xp = x + ((size_t)(b0 + pb) * S_LEN) * I_DIM + pi;
    const int skt = pi >> 5, skc = pi & 31, srw = 4 * pb;

    // ---- zero staging (h0=0, pad cols, unused rows) ----
    for (int i = u; i < 1280; i += 1024) {
        ((unsigned*)Hst)[i] = 0u; ((unsigned*)Xst)[i] = 0u;
    }
    __syncthreads();
    if (isp) {                       // stage x(0)->X[0], x(1)->X[1]
        Xst[0][skt][srw][skc] = (_Float16)xp[0];
        Xst[1][skt][srw][skc] = (_Float16)xp[I_DIM];
    }
    __syncthreads();

#define MM2(ACC, LACC, A, WN) \
    ACC  = __builtin_amdgcn_mfma_f32_16x16x32_f16(A, WN##h, ACC,  0, 0, 0); \
    LACC = __builtin_amdgcn_mfma_f32_16x16x32_f16(A, WN##l, LACC, 0, 0, 0);

    // ---- prologue: accA = x(0)·W_ih from X[0] (bias added at combine) ----
    f32x4 aA, lA, aB, lB;
    aA = (f32x4){0.f,0.f,0.f,0.f}; lA = aA; aB = aA; lB = aA;
    {
        const f16x8 xf0 = *(const f16x8*)&Xst[0][0][c][hk * 8];
        const f16x8 xf1 = *(const f16x8*)&Xst[0][1][c][hk * 8];
        MM2(aA, lA, xf0, wx0) MM2(aA, lA, xf1, wx1)
    }
    __syncthreads();                 // X[0] reads done before step-0 staging

    // ---- scan; ONE barrier per step; unrolled x2 for acc handoff ----
#define STEP(T, AP, LP, AN, LN, CUR, NXT) { \
    float xnext = 0.0f; \
    const bool dox = isp && ((T) + 2 < S_LEN); \
    if (dox) xnext = xp[(size_t)((T) + 2) * I_DIM];      /* issue early */ \
    const f16x8 ah0 = *(const f16x8*)&Hst[CUR][0][c][hk * 8]; \
    const f16x8 ah1 = *(const f16x8*)&Hst[CUR][1][c][hk * 8]; \
    const f16x8 xh0 = *(const f16x8*)&Xst[NXT][0][c][hk * 8]; \
    const f16x8 xh1 = *(const f16x8*)&Xst[NXT][1][c][hk * 8]; \
    MM2(AP, LP, ah0, wh0) MM2(AP, LP, ah1, wh1)          /* h-part */ \
    const float v  = AP[0] + fmaf(ILO, LP[0], bias);     /* own gate */ \
    const float s4  = __shfl_xor(v, 4); \
    const float s8  = __shfl_xor(v, 8); \
    const float s12 = __shfl_xor(v, 12); \
    AN = (f32x4){0.f,0.f,0.f,0.f}; LN = AN; \
    MM2(AN, LN, xh0, wx0) MM2(AN, LN, xh1, wx1)          /* x-part t+1 */ \
    if (c < 4) {                                         /* g==0 lanes */ \
        const float gi = sigm(v),       gf = sigm(s4); \
        const float gg = tanh_fast(s8), go = sigm(s12); \
        cst = fmaf(gf, cst, gi * gg); \
        const float hv = go * tanh_fast(cst); \
        Hst[NXT][unit >> 5][4 * hk][unit & 31] = (_Float16)hv; \
    } else if (dox) { \
        Xst[CUR][skt][srw][skc] = (_Float16)xnext; \
    } \
    __syncthreads(); \
}

    for (int t = 0; t < S_LEN; t += 2) {
        STEP(t,     aA, lA, aB, lB, 0, 1)
        STEP(t + 1, aB, lB, aA, lA, 1, 0)
    }
#undef STEP
#undef MM2

    // ---- classifier head; h_last (fp16) in H[0], rows 4b ----
    if (u < BB * F1_DIM) {           // 128 threads
        const int b = u >> 5, f = u & 31;
        float acc = b1[f];
        #pragma unroll
        for (int j = 0; j < H_DIM; ++j) {
            const float hj = (float)Hst[0][j >> 5][4 * b][j & 31];
            acc = fmaf(hj, W1[f * H_DIM + j], acc);
        }
        f1buf[b][f] = fmaxf(acc, 0.0f);
    }
    __syncthreads();
    if (u < BB * C_DIM) {            // 8 threads
        const int b = u >> 1, cl = u & 1;
        float acc = b2[cl];
        #pragma unroll
        for (int f = 0; f < F1_DIM; ++f)
            acc = fmaf(f1buf[b][f], W2[cl * F1_DIM + f], acc);
        out[(size_t)(b0 + b) * C_DIM + cl] = acc;
    }
}

extern "C" void kernel_launch(void* const* d_in, const int* in_sizes, int n_in,
                              void* d_out, int out_size, void* d_ws, size_t ws_size,
                              hipStream_t stream) {
    const float* x   = (const float*)d_in[0];
    const float* Wih = (const float*)d_in[1];
    const float* Whh = (const float*)d_in[2];
    const float* bih = (const float*)d_in[3];
    const float* bhh = (const float*)d_in[4];
    const float* W1  = (const float*)d_in[5];
    const float* b1  = (const float*)d_in[6];
    const float* W2  = (const float*)d_in[7];
    const float* b2  = (const float*)d_in[8];
    float* out = (float*)d_out;

    hipLaunchKernelGGL(lstm_mfma, dim3(256), dim3(1024), 0, stream,
                       x, Wih, Whh, bih, bhh, W1, b1, W2, b2, out);
}

// Round 13
// 210.434 us; speedup vs baseline: 1.8131x; 1.5809x over previous
//
#include <hip/hip_runtime.h>
#include <math.h>

// LSTMClassifier fused kernel for MI355X (gfx950) — round 12
// Chunked two-phase structure: per 16-step chunk, phase 1 computes
// xg = x·W_ih^T + bias for 4 batches x 16 steps via a well-shaped MFMA GEMM
// (M=64 rows, zero waste) into LDS (f32); phase 2 scans 16 steps doing ONLY
// the recurrent h·W_hh part: 2 ds_read_b128 + 8 MFMA + 2 shfl + 1 xg b128
// read + 1 h-write per wave per step. Cuts DS-pipe traffic ~3x vs r11.
// fp16 2-term weights (hi + lo*2^11), fp16 A-side, f32 xg (proven 9.8e-4).
// 512 threads (8 waves, 2/SIMD), grid=256 (1 block/CU), 4 batch/block.
// Gate-permuted N: wave w tileA = gates i|f of units 8w..8w+7, tileB = g|o.

#define S_LEN  512
#define I_DIM  50
#define H_DIM  64
#define BB     4
#define TC     16                    // timesteps per chunk
#define NCH    (S_LEN / TC)          // 32 chunks
#define KROW   40                    // Hst row stride (fp16)
#define XROW   72                    // Xstage row stride (fp16)
#define NXELEM (BB * TC * I_DIM)     // 3200 x-elems per chunk
#define F1_DIM 32
#define C_DIM  2
#define ILO (1.0f / 2048.0f)

typedef __attribute__((ext_vector_type(8))) _Float16 f16x8;
typedef __attribute__((ext_vector_type(4))) float    f32x4;

__device__ __forceinline__ float fast_rcp(float x) { return __builtin_amdgcn_rcpf(x); }
__device__ __forceinline__ float sigm(float v) { return fast_rcp(1.0f + __expf(-v)); }
__device__ __forceinline__ float tanh_fast(float v) {
    return 1.0f - 2.0f * fast_rcp(__expf(2.0f * v) + 1.0f);
}

// Weight fragment pair: hi = fp16(w), lo = fp16((w - hi) * 2048).
// ktg 0,1 -> W_ih (k<50, else 0); ktg 2,3 -> W_hh (k-64).
__device__ __forceinline__ void load_wfrag(const float* __restrict__ Wih,
                                           const float* __restrict__ Whh,
                                           int ktg, int row, int hk,
                                           f16x8& bh, f16x8& bl) {
    #pragma unroll
    for (int j = 0; j < 8; ++j) {
        const int kk = ktg * 32 + hk * 8 + j;
        float wv;
        if (ktg < 2) wv = (kk < I_DIM) ? Wih[row * I_DIM + kk] : 0.0f;
        else         wv = Whh[row * H_DIM + (kk - 64)];
        const _Float16 h = (_Float16)wv;
        bh[j] = h;
        bl[j] = (_Float16)((wv - (float)h) * 2048.0f);
    }
}

__global__ __launch_bounds__(512, 2)
void lstm_mfma(const float* __restrict__ x,
               const float* __restrict__ W_ih, const float* __restrict__ W_hh,
               const float* __restrict__ b_ih, const float* __restrict__ b_hh,
               const float* __restrict__ W1,  const float* __restrict__ b1,
               const float* __restrict__ W2,  const float* __restrict__ b2,
               float* __restrict__ out)
{
    __shared__ __align__(16) _Float16 Hst[2][2][16][KROW];        // h, dbuf
    __shared__ __align__(16) _Float16 Xstage[BB * TC][XROW];      // x chunk (M=64 rows)
    __shared__ __align__(16) float    XG[TC][BB][H_DIM][4];       // xg: (i,f,g,o) per (t,b,unit)
    __shared__ float f1buf[BB][F1_DIM];

    const int u  = threadIdx.x;      // 0..511
    const int w  = u >> 6;           // wave 0..7
    const int l  = u & 63;
    const int c  = l & 15;           // n-col / A-row
    const int hk = l >> 4;           // k-quarter; batch in cell phase
    const int b0 = blockIdx.x * BB;

    // gate-permuted N: tileA col c -> gate c>>3, unit 8w+(c&7); tileB: gate 2+(c>>3)
    const int uu = 8 * w + (c & 7);
    const int gA = c >> 3;
    const int r0 = gA * H_DIM + uu;
    const int r1 = (gA + 2) * H_DIM + uu;

    // ---- resident weight fragments: x-ktiles (0,1) and h-ktiles (2,3) ----
#define LW(nm, ktg, row) f16x8 nm##h, nm##l; \
    load_wfrag(W_ih, W_hh, ktg, row, hk, nm##h, nm##l);
    LW(wx0a, 0, r0) LW(wx1a, 1, r0) LW(wh0a, 2, r0) LW(wh1a, 3, r0)
    LW(wx0b, 0, r1) LW(wx1b, 1, r1) LW(wh0b, 2, r1) LW(wh1b, 3, r1)
#undef LW

    const float bA = b_ih[r0] + b_hh[r0];
    const float bB = b_ih[r1] + b_hh[r1];
    float cst = 0.0f;                // cell state (batch hk, unit 8w+c), lanes c<8

    // ---- zero Hst (h0=0) and Xstage (k-pad) once ----
    for (int i = u; i < 1280; i += 512) ((unsigned*)Hst)[i] = 0u;
    for (int i = u; i < 2304; i += 512) ((unsigned*)Xstage)[i] = 0u;
    __syncthreads();

    // x element mapping: idx -> (batch bb_, step tt_, input ii_)
#define XE(E, BODY) { const int idx = u + (E) * 512; if (idx < NXELEM) { \
        const int bb_ = idx / (TC * I_DIM); \
        const int rm_ = idx - bb_ * (TC * I_DIM); \
        const int tt_ = rm_ / I_DIM; \
        const int ii_ = rm_ - tt_ * I_DIM; BODY } }

    // stage x chunk 0
    XE(0, Xstage[bb_ * TC + tt_][ii_] = (_Float16)x[(size_t)(b0 + bb_) * (S_LEN * I_DIM) + tt_ * I_DIM + ii_];)
    XE(1, Xstage[bb_ * TC + tt_][ii_] = (_Float16)x[(size_t)(b0 + bb_) * (S_LEN * I_DIM) + tt_ * I_DIM + ii_];)
    XE(2, Xstage[bb_ * TC + tt_][ii_] = (_Float16)x[(size_t)(b0 + bb_) * (S_LEN * I_DIM) + tt_ * I_DIM + ii_];)
    XE(3, Xstage[bb_ * TC + tt_][ii_] = (_Float16)x[(size_t)(b0 + bb_) * (S_LEN * I_DIM) + tt_ * I_DIM + ii_];)
    XE(4, Xstage[bb_ * TC + tt_][ii_] = (_Float16)x[(size_t)(b0 + bb_) * (S_LEN * I_DIM) + tt_ * I_DIM + ii_];)
    XE(5, Xstage[bb_ * TC + tt_][ii_] = (_Float16)x[(size_t)(b0 + bb_) * (S_LEN * I_DIM) + tt_ * I_DIM + ii_];)
    XE(6, Xstage[bb_ * TC + tt_][ii_] = (_Float16)x[(size_t)(b0 + bb_) * (S_LEN * I_DIM) + tt_ * I_DIM + ii_];)
    __syncthreads();

#define MM2(ACC, LACC, A, WN) \
    ACC  = __builtin_amdgcn_mfma_f32_16x16x32_f16(A, WN##h, ACC,  0, 0, 0); \
    LACC = __builtin_amdgcn_mfma_f32_16x16x32_f16(A, WN##l, LACC, 0, 0, 0);

    float xr0, xr1, xr2, xr3, xr4, xr5, xr6;

    for (int ch = 0; ch < NCH; ++ch) {
        // ======== phase 1: xg GEMM for this chunk (M-tile mt = batch) ========
        #pragma unroll
        for (int mt = 0; mt < BB; ++mt) {
            const f16x8 a0 = *(const f16x8*)&Xstage[mt * 16 + c][hk * 8];
            const f16x8 a1 = *(const f16x8*)&Xstage[mt * 16 + c][32 + hk * 8];
            f32x4 aP = {bA, bA, bA, bA}, lP = {0.f, 0.f, 0.f, 0.f};
            f32x4 aQ = {bB, bB, bB, bB}, lQ = {0.f, 0.f, 0.f, 0.f};
            MM2(aP, lP, a0, wx0a) MM2(aP, lP, a1, wx1a)
            MM2(aQ, lQ, a0, wx0b) MM2(aQ, lQ, a1, wx1b)
            // D row = hk*4+i -> step t; col -> (gate, unit)
            #pragma unroll
            for (int i = 0; i < 4; ++i) {
                XG[hk * 4 + i][mt][uu][gA]     = aP[i] + ILO * lP[i];
                XG[hk * 4 + i][mt][uu][gA + 2] = aQ[i] + ILO * lQ[i];
            }
        }
        __syncthreads();

        // issue x loads for next chunk (consumed after the scan)
        const bool hn = (ch + 1 < NCH);
        if (hn) {
            XE(0, xr0 = x[(size_t)(b0 + bb_) * (S_LEN * I_DIM) + ((ch + 1) * TC + tt_) * I_DIM + ii_];)
            XE(1, xr1 = x[(size_t)(b0 + bb_) * (S_LEN * I_DIM) + ((ch + 1) * TC + tt_) * I_DIM + ii_];)
            XE(2, xr2 = x[(size_t)(b0 + bb_) * (S_LEN * I_DIM) + ((ch + 1) * TC + tt_) * I_DIM + ii_];)
            XE(3, xr3 = x[(size_t)(b0 + bb_) * (S_LEN * I_DIM) + ((ch + 1) * TC + tt_) * I_DIM + ii_];)
            XE(4, xr4 = x[(size_t)(b0 + bb_) * (S_LEN * I_DIM) + ((ch + 1) * TC + tt_) * I_DIM + ii_];)
            XE(5, xr5 = x[(size_t)(b0 + bb_) * (S_LEN * I_DIM) + ((ch + 1) * TC + tt_) * I_DIM + ii_];)
            XE(6, xr6 = x[(size_t)(b0 + bb_) * (S_LEN * I_DIM) + ((ch + 1) * TC + tt_) * I_DIM + ii_];)
        }

        // ======== phase 2: scan TC steps (h-recurrence only) ========
#define SSTEP(T, CUR, NXT) { \
        const f32x4 xg4 = *(const f32x4*)&XG[T][hk][8 * w + (c & 7)][0]; \
        const f16x8 ah0 = *(const f16x8*)&Hst[CUR][0][c][hk * 8]; \
        const f16x8 ah1 = *(const f16x8*)&Hst[CUR][1][c][hk * 8]; \
        f32x4 aA = {0.f, 0.f, 0.f, 0.f}, lA = aA, aB = aA, lB = aA; \
        MM2(aA, lA, ah0, wh0a) MM2(aA, lA, ah1, wh1a) \
        MM2(aB, lB, ah0, wh0b) MM2(aB, lB, ah1, wh1b) \
        const float vA = aA[0] + ILO * lA[0]; \
        const float vB = aB[0] + ILO * lB[0]; \
        const float yA = __shfl_xor(vA, 8); \
        const float yB = __shfl_xor(vB, 8); \
        if (c < 8) { \
            const float gi = sigm(vA + xg4[0]); \
            const float gf = sigm(yA + xg4[1]); \
            const float gg = tanh_fast(vB + xg4[2]); \
            const float go = sigm(yB + xg4[3]); \
            cst = fmaf(gf, cst, gi * gg); \
            const float hv = go * tanh_fast(cst); \
            const int un = 8 * w + c; \
            Hst[NXT][un >> 5][4 * hk][un & 31] = (_Float16)hv; \
        } \
        __syncthreads(); }

        #pragma unroll
        for (int tt = 0; tt < TC; tt += 2) {
            SSTEP(tt,     0, 1)
            SSTEP(tt + 1, 1, 0)
        }
#undef SSTEP

        // commit next chunk's x into Xstage (free during next phase 1 only)
        if (hn) {
            XE(0, Xstage[bb_ * TC + tt_][ii_] = (_Float16)xr0;)
            XE(1, Xstage[bb_ * TC + tt_][ii_] = (_Float16)xr1;)
            XE(2, Xstage[bb_ * TC + tt_][ii_] = (_Float16)xr2;)
            XE(3, Xstage[bb_ * TC + tt_][ii_] = (_Float16)xr3;)
            XE(4, Xstage[bb_ * TC + tt_][ii_] = (_Float16)xr4;)
            XE(5, Xstage[bb_ * TC + tt_][ii_] = (_Float16)xr5;)
            XE(6, Xstage[bb_ * TC + tt_][ii_] = (_Float16)xr6;)
        }
        __syncthreads();
    }
#undef MM2
#undef XE

    // ---- classifier head; h_last (fp16) in Hst[0], rows 4b ----
    if (u < BB * F1_DIM) {           // 128 threads
        const int b = u >> 5, f = u & 31;
        float acc = b1[f];
        #pragma unroll
        for (int j = 0; j < H_DIM; ++j) {
            const float hj = (float)Hst[0][j >> 5][4 * b][j & 31];
            acc = fmaf(hj, W1[f * H_DIM + j], acc);
        }
        f1buf[b][f] = fmaxf(acc, 0.0f);
    }
    __syncthreads();
    if (u < BB * C_DIM) {            // 8 threads
        const int b = u >> 1, cl = u & 1;
        float acc = b2[cl];
        #pragma unroll
        for (int f = 0; f < F1_DIM; ++f)
            acc = fmaf(f1buf[b][f], W2[cl * F1_DIM + f], acc);
        out[(size_t)(b0 + b) * C_DIM + cl] = acc;
    }
}

extern "C" void kernel_launch(void* const* d_in, const int* in_sizes, int n_in,
                              void* d_out, int out_size, void* d_ws, size_t ws_size,
                              hipStream_t stream) {
    const float* x   = (const float*)d_in[0];
    const float* Wih = (const float*)d_in[1];
    const float* Whh = (const float*)d_in[2];
    const float* bih = (const float*)d_in[3];
    const float* bhh = (const float*)d_in[4];
    const float* W1  = (const float*)d_in[5];
    const float* b1  = (const float*)d_in[6];
    const float* W2  = (const float*)d_in[7];
    const float* b2  = (const float*)d_in[8];
    float* out = (float*)d_out;

    hipLaunchKernelGGL(lstm_mfma, dim3(256), dim3(512), 0, stream,
                       x, Wih, Whh, bih, bhh, W1, b1, W2, b2, out);
}